// Round 6
// baseline (125.020 us; speedup 1.0000x reference)
//
#include <hip/hip_runtime.h>
#include <hip/hip_bf16.h>
#include <stdint.h>

#define IN_F   128
#define OUT_F  128
#define NUM_F  8
#define NROWS  (16*4096)

typedef __bf16  bf16x8  __attribute__((ext_vector_type(8)));
typedef float   f32x16  __attribute__((ext_vector_type(16)));

// Wp layout: [half][fb][s][t][lane][8 bf16]; half-stride = 9*8*2*64*16 = 147456 B
#define LDS_HALF  (9*8*2*64*16)
#define WP_CHUNKS (2*9*8*2*64)
#define WP_BYTES  (WP_CHUNKS*16)
#define BIAS_OFF  WP_BYTES

// ---------------- prep: build permuted bf16 weight + bias ----------------
__global__ __launch_bounds__(256) void skan_prep(
    const float* __restrict__ base_w,   // [OUT_F][IN_F]
    const float* __restrict__ scale,    // [OUT_F]
    const float* __restrict__ coef,     // [GROUPS][1][NUM_F]
    const float* __restrict__ conv_w,   // [NUM_F][OUT_F][IN_F]
    const float* __restrict__ conv_b,   // [NUM_F][OUT_F]
    __bf16* __restrict__ Wp, float* __restrict__ bias)
{
    int gid = blockIdx.x * 256 + threadIdx.x;        // 0..18431
    int flat = gid;
    int l  = flat & 63;  flat >>= 6;
    int t2 = flat & 1;   flat >>= 1;
    int s  = flat & 7;   flat >>= 3;
    int fb = flat % 9;
    int h2 = flat / 9;                               // out-half
    int n  = h2 * 64 + t2 * 32 + (l & 31);           // global out col
    int k0 = s * 16 + (l >> 5) * 8;
    __bf16* dst = Wp + (size_t)gid * 8;
    if (fb == 0) {
        const float4* b4 = (const float4*)(base_w + n * IN_F + k0);
        float4 a = b4[0], b = b4[1];
        dst[0]=(__bf16)a.x; dst[1]=(__bf16)a.y; dst[2]=(__bf16)a.z; dst[3]=(__bf16)a.w;
        dst[4]=(__bf16)b.x; dst[5]=(__bf16)b.y; dst[6]=(__bf16)b.z; dst[7]=(__bf16)b.w;
    } else {
        int f = fb - 1;
        float sc = scale[n];
        const float4* c4 = (const float4*)(conv_w + ((size_t)f * OUT_F + n) * IN_F + k0);
        float4 a = c4[0], b = c4[1];
        // group = k/16; k0 is 8-aligned so all 8 k's share group (k0>>4)
        float mc = coef[(k0 >> 4) * NUM_F + f] * sc;
        dst[0]=(__bf16)(a.x*mc); dst[1]=(__bf16)(a.y*mc); dst[2]=(__bf16)(a.z*mc); dst[3]=(__bf16)(a.w*mc);
        dst[4]=(__bf16)(b.x*mc); dst[5]=(__bf16)(b.y*mc); dst[6]=(__bf16)(b.z*mc); dst[7]=(__bf16)(b.w*mc);
    }
    if (gid < OUT_F) {
        float b = 0.f;
        #pragma unroll
        for (int f = 0; f < NUM_F; ++f) b += conv_b[f * OUT_F + gid];
        bias[gid] = b * scale[gid];
    }
}

// ---------------- main fused kernel ----------------
__device__ __forceinline__ void gld_lds16(const void* g, void* l) {
    __builtin_amdgcn_global_load_lds(
        (const __attribute__((address_space(1))) uint32_t*)g,
        (__attribute__((address_space(3))) uint32_t*)l, 16, 0, 0);
}

__device__ __forceinline__ uint32_t pkbf(float a, float b) {
    __bf16 x = (__bf16)a, y = (__bf16)b;
    uint16_t ux, uy;
    __builtin_memcpy(&ux, &x, 2);
    __builtin_memcpy(&uy, &y, 2);
    return (uint32_t)ux | ((uint32_t)uy << 16);
}
__device__ __forceinline__ float upk_lo(uint32_t p) { return __uint_as_float(p << 16); }
__device__ __forceinline__ float upk_hi(uint32_t p) { return __uint_as_float(p & 0xffff0000u); }

__device__ __forceinline__ bf16x8 mkfrag(uint32_t p0, uint32_t p1, uint32_t p2, uint32_t p3) {
    uint32_t u[4] = {p0, p1, p2, p3};
    bf16x8 r;
    __builtin_memcpy(&r, u, 16);
    return r;
}

// 512 threads (8 waves), min 2 waves/EU -> VGPR <= 256; 144 KB LDS -> 1 block/CU,
// 8 waves/CU = 2 waves/SIMD; grid = 256 = exactly one block per CU (single round).
__global__ __launch_bounds__(512, 2) void skan_main(
    const float* __restrict__ x,        // [NROWS][IN_F]
    const __bf16* __restrict__ Wp,
    const float* __restrict__ bias,
    float* __restrict__ out)            // [NROWS][OUT_F]
{
    __shared__ __align__(16) char sB[LDS_HALF];   // this half's W, fully resident

    const int tid  = threadIdx.x;
    const int w    = tid >> 6;          // wave 0..7
    const int l    = tid & 63;
    const int hl   = l & 31;
    const int h    = l >> 5;
    const int bx   = blockIdx.x;
    // blocks bx and bx+128 share x rows and land on the same XCD (128 % 8 == 0)
    const int rowb = bx & 127;
    const int half = bx >> 7;
    const int m0   = rowb * 512 + w * 64;   // wave's 64-row base

    // ---- stage all 9 fb blocks for this half (18 x 16B per thread) ----
    const char* src = (const char*)Wp + (size_t)half * LDS_HALF;
    #pragma unroll
    for (int i = 0; i < 18; ++i) {
        int off = (i * 512 + tid) * 16;         // wave-uniform base + lane*16
        gld_lds16(src + off, sB + off);
    }

    // ---- load x rows m0+32g+hl, cols s*16 + h*8 + j; pack to bf16 ----
    const float4* x4 = (const float4*)x;
    uint32_t xe[2][32];                 // [g][s*4 + jp]
    #pragma unroll
    for (int g = 0; g < 2; ++g) {
        size_t base = (size_t)(m0 + 32 * g + hl) * 32 + 2 * h;
        #pragma unroll
        for (int s = 0; s < 8; ++s) {
            float4 a = x4[base + 4 * s];
            float4 b = x4[base + 4 * s + 1];
            xe[g][4*s+0] = pkbf(a.x, a.y);
            xe[g][4*s+1] = pkbf(a.z, a.w);
            xe[g][4*s+2] = pkbf(b.x, b.y);
            xe[g][4*s+3] = pkbf(b.z, b.w);
        }
    }

    f32x16 acc[2][2];                   // [g][t]
    #pragma unroll
    for (int g = 0; g < 2; ++g)
        #pragma unroll
        for (int t = 0; t < 2; ++t)
            #pragma unroll
            for (int r = 0; r < 16; ++r) acc[g][t][r] = 0.f;

    __syncthreads();   // staging drained; the ONLY barrier

    const bf16x8* bp = (const bf16x8*)sB;

    #pragma unroll
    for (int s = 0; s < 8; ++s) {
        // ---- fb0: silu path, both row-groups ----
        {
            bf16x8 af[2];
            #pragma unroll
            for (int g = 0; g < 2; ++g) {
                uint32_t pr[4];
                #pragma unroll
                for (int jp = 0; jp < 4; ++jp) {
                    uint32_t p = xe[g][4*s+jp];
                    float lo = upk_lo(p), hi = upk_hi(p);
                    float slo = lo * __builtin_amdgcn_rcpf(1.0f + __expf(-lo));
                    float shi = hi * __builtin_amdgcn_rcpf(1.0f + __expf(-hi));
                    pr[jp] = pkbf(slo, shi);
                }
                af[g] = mkfrag(pr[0], pr[1], pr[2], pr[3]);
            }
            #pragma unroll
            for (int t = 0; t < 2; ++t) {
                bf16x8 b = bp[(s * 2 + t) * 64 + l];
                acc[0][t] = __builtin_amdgcn_mfma_f32_32x32x16_bf16(af[0], b, acc[0][t], 0, 0, 0);
                acc[1][t] = __builtin_amdgcn_mfma_f32_32x32x16_bf16(af[1], b, acc[1][t], 0, 0, 0);
            }
        }
        // ---- spline: sin(f*x) via s_f = 2cos(x)*s_{f-1} - s_{f-2} ----
        float sp[16], sp2[16], tc[16];   // [g*8 + j]
        #pragma unroll
        for (int g = 0; g < 2; ++g)
            #pragma unroll
            for (int jp = 0; jp < 4; ++jp) {
                uint32_t p = xe[g][4*s+jp];
                float lo = upk_lo(p), hi = upk_hi(p);
                float rl = __builtin_amdgcn_fractf(lo * 0.15915494309189535f);
                float rh = __builtin_amdgcn_fractf(hi * 0.15915494309189535f);
                int j0 = g * 8 + 2 * jp;
                sp[j0]    = __builtin_amdgcn_sinf(rl);
                sp[j0+1]  = __builtin_amdgcn_sinf(rh);
                tc[j0]    = 2.0f * __builtin_amdgcn_cosf(rl);
                tc[j0+1]  = 2.0f * __builtin_amdgcn_cosf(rh);
                sp2[j0]   = 0.0f;
                sp2[j0+1] = 0.0f;
            }
        #pragma unroll
        for (int f = 1; f <= 8; ++f) {
            bf16x8 a0 = mkfrag(pkbf(sp[0], sp[1]),  pkbf(sp[2], sp[3]),
                               pkbf(sp[4], sp[5]),  pkbf(sp[6], sp[7]));
            bf16x8 a1 = mkfrag(pkbf(sp[8], sp[9]),  pkbf(sp[10], sp[11]),
                               pkbf(sp[12], sp[13]), pkbf(sp[14], sp[15]));
            #pragma unroll
            for (int t = 0; t < 2; ++t) {
                bf16x8 b = bp[((f * 8 + s) * 2 + t) * 64 + l];
                acc[0][t] = __builtin_amdgcn_mfma_f32_32x32x16_bf16(a0, b, acc[0][t], 0, 0, 0);
                acc[1][t] = __builtin_amdgcn_mfma_f32_32x32x16_bf16(a1, b, acc[1][t], 0, 0, 0);
            }
            if (f < 8) {
                #pragma unroll
                for (int i = 0; i < 16; ++i) {
                    float sn = __builtin_fmaf(tc[i], sp[i], -sp2[i]);
                    sp2[i] = sp[i];
                    sp[i]  = sn;
                }
            }
        }
    }

    // ---- epilogue: direct stores (128-B contiguous per half-wave) ----
    // D layout: col = lane&31, row = (r&3) + 8*(r>>2) + 4*h (+ 32*g)
    #pragma unroll
    for (int g = 0; g < 2; ++g)
        #pragma unroll
        for (int t = 0; t < 2; ++t) {
            float bv = bias[half * 64 + t * 32 + hl];
            #pragma unroll
            for (int r = 0; r < 16; ++r) {
                int row = (r & 3) + 8 * (r >> 2) + 4 * h + 32 * g;
                out[(size_t)(m0 + row) * OUT_F + half * 64 + t * 32 + hl] = acc[g][t][r] + bv;
            }
        }
}

extern "C" void kernel_launch(void* const* d_in, const int* in_sizes, int n_in,
                              void* d_out, int out_size, void* d_ws, size_t ws_size,
                              hipStream_t stream) {
    const float* x      = (const float*)d_in[0];
    // d_in[1] = grid (values 1..8, folded into the recurrence)
    const float* base_w = (const float*)d_in[2];
    const float* scale  = (const float*)d_in[3];
    const float* coef   = (const float*)d_in[4];
    const float* conv_w = (const float*)d_in[5];
    const float* conv_b = (const float*)d_in[6];
    __bf16* Wp   = (__bf16*)d_ws;
    float*  bias = (float*)((char*)d_ws + BIAS_OFF);
    float*  out  = (float*)d_out;

    skan_prep<<<WP_CHUNKS / 256, 256, 0, stream>>>(base_w, scale, coef, conv_w, conv_b, Wp, bias);
    // 128 row-blocks x 2 out-halves = 256 blocks (1/CU, single round), 8 waves each
    skan_main<<<256, 512, 0, stream>>>(x, Wp, bias, out);
}